// Round 1
// baseline (188.064 us; speedup 1.0000x reference)
//
#include <hip/hip_runtime.h>
#include <stdint.h>
#include <stddef.h>

typedef _Float16 f16_t;
typedef _Float16 f16x4 __attribute__((ext_vector_type(4)));
typedef _Float16 f16x8 __attribute__((ext_vector_type(8)));
typedef float f32x4 __attribute__((ext_vector_type(4)));

#define AS_G __attribute__((address_space(1)))
#define AS_L __attribute__((address_space(3)))

__device__ __forceinline__ void gload_lds16(const void* g, void* l) {
  __builtin_amdgcn_global_load_lds((AS_G void*)g, (AS_L void*)l, 16, 0, 0);
}

// ---------------- small prep kernels ----------------

// fp32 -> fp16 elementwise (vectorized x4)
__global__ void cvt_f16_kernel(const float* __restrict__ in, f16_t* __restrict__ out, int n4) {
  int i = blockIdx.x * blockDim.x + threadIdx.x;
  if (i >= n4) return;
  f32x4 v = ((const f32x4*)in)[i];
  f16x4 o;
  o.x = (f16_t)v.x; o.y = (f16_t)v.y; o.z = (f16_t)v.z; o.w = (f16_t)v.w;
  ((f16x4*)out)[i] = o;
}

// WvT[c][d] = Wv[d][c], fp32 -> fp16, LDS-tiled transpose (1024x1024)
__global__ void transpose_cvt_kernel(const float* __restrict__ in, f16_t* __restrict__ out) {
  __shared__ float tile[32][33];
  const int bx = blockIdx.x, by = blockIdx.y;
  const int tx = threadIdx.x, ty = threadIdx.y;
#pragma unroll
  for (int i = 0; i < 32; i += 8)
    tile[ty + i][tx] = in[(size_t)(by * 32 + ty + i) * 1024 + bx * 32 + tx];
  __syncthreads();
#pragma unroll
  for (int i = 0; i < 32; i += 8)
    out[(size_t)(bx * 32 + ty + i) * 1024 + by * 32 + tx] = (f16_t)tile[tx][ty + i];
}

// bconst[e] = (sum_k w_k) * dot(Wo[e,:], bv) + bo[e]
__global__ void bconst_kernel(const float* __restrict__ Wo, const float* __restrict__ bv,
                              const float* __restrict__ bo, const float* __restrict__ nw,
                              int Kw, float* __restrict__ bc) {
  const int e = blockIdx.x;
  const int t = threadIdx.x;
  float sw = 0.f;
  for (int k = 0; k < Kw; ++k) sw += nw[k];
  float p = 0.f;
  for (int d = t; d < 1024; d += 256) p += Wo[(size_t)e * 1024 + d] * bv[d];
  __shared__ float red[256];
  red[t] = p;
  __syncthreads();
  for (int s = 128; s > 0; s >>= 1) {
    if (t < s) red[t] += red[t + s];
    __syncthreads();
  }
  if (t == 0) bc[e] = sw * red[0] + bo[e];
}

// xavg[r][:] = w0*x[r-1] + w1*x[r] + w2*x[r+1]  (clamped within each batch of T rows)
// 8 rows per block, 256 threads, one float4 column-chunk per thread, rolling regs.
__global__ void xavg_kernel(const float* __restrict__ x, const float* __restrict__ nw,
                            f16_t* __restrict__ out) {
  const int T = 4096, D = 1024;
  const int base = blockIdx.x * 8;          // global row (b*T + t), 8 rows never straddle batch
  const int t0 = base & (T - 1);
  const int col = threadIdx.x * 4;
  const float w0 = nw[0], w1 = nw[1], w2 = nw[2];
  const float* xb = x + (size_t)base * D + col;
  f32x4 a = *(const f32x4*)(xb + (t0 == 0 ? 0 : -D));
  f32x4 b = *(const f32x4*)(xb);
  f16_t* ob = out + (size_t)base * D + col;
#pragma unroll
  for (int g = 0; g < 8; ++g) {
    f32x4 c;
    if (t0 + g == T - 1) c = b;
    else c = *(const f32x4*)(xb + (size_t)(g + 1) * D);
    f32x4 y = w0 * a + w1 * b + w2 * c;
    f16x4 o;
    o.x = (f16_t)y.x; o.y = (f16_t)y.y; o.z = (f16_t)y.z; o.w = (f16_t)y.w;
    *(f16x4*)(ob + (size_t)g * D) = o;
    a = b;
    b = c;
  }
}

// ---------------- MFMA GEMM: C[M][N] = A[M][K] * Bt[N][K]^T (+ bias) ----------------
// 128x128 tile, BK=32, 4 waves (2x2), 16x16x32 f16 MFMA, global_load_lds width-16.

template <typename OutT, bool BIAS>
__global__ __launch_bounds__(256) void gemm_bt_kernel(const f16_t* __restrict__ A,
                                                      const f16_t* __restrict__ Bt,
                                                      OutT* __restrict__ C,
                                                      const float* __restrict__ bias,
                                                      int M, int N, int K) {
  __shared__ __align__(16) f16_t sA[128 * 32];
  __shared__ __align__(16) f16_t sB[128 * 32];
  const int tid = threadIdx.x;
  const int l = tid & 63;
  const int w = tid >> 6;
  const int wr = w >> 1;
  const int wc = w & 1;
  const int nMT = M >> 7;
  const int bid = blockIdx.x;
  const int mt = bid % nMT;          // same-mtile blocks share bid%8 -> same XCD (A-panel L2 reuse)
  const int nt = bid / nMT;
  const int m0 = mt << 7;
  const int n0 = nt << 7;

  // staging: thread t covers tile row (t>>2), 16B chunk (t&3); lane-linear in LDS
  const int srow = (w << 4) + (l >> 2);  // 0..63
  const int scol = (l & 3) << 3;         // element offset 0,8,16,24
  const size_t aoff0 = (size_t)(m0 + srow) * K + scol;
  const size_t boff0 = (size_t)(n0 + srow) * K + scol;
  f16_t* ldsA = sA + (w << 9);  // wave-uniform base, +lane*16B by HW
  f16_t* ldsB = sB + (w << 9);

  f32x4 acc[4][4];
#pragma unroll
  for (int i = 0; i < 4; ++i)
#pragma unroll
    for (int j = 0; j < 4; ++j) acc[i][j] = f32x4{0.f, 0.f, 0.f, 0.f};

  const int ka = (l >> 4) << 3;        // K offset of this lane's fragment
  const int ar = (wr << 6) + (l & 15); // A row within tile
  const int br = (wc << 6) + (l & 15); // Bt row (=N col) within tile

  const int nK = K >> 5;
  for (int kt = 0; kt < nK; ++kt) {
    const int kb = kt << 5;
    gload_lds16(A + aoff0 + kb, ldsA);
    gload_lds16(A + aoff0 + ((size_t)K << 6) + kb, ldsA + 2048);
    gload_lds16(Bt + boff0 + kb, ldsB);
    gload_lds16(Bt + boff0 + ((size_t)K << 6) + kb, ldsB + 2048);
    __syncthreads();
    f16x8 af[4], bfr[4];
#pragma unroll
    for (int m = 0; m < 4; ++m) af[m] = *(const f16x8*)(sA + ((ar + (m << 4)) << 5) + ka);
#pragma unroll
    for (int n = 0; n < 4; ++n) bfr[n] = *(const f16x8*)(sB + ((br + (n << 4)) << 5) + ka);
#pragma unroll
    for (int m = 0; m < 4; ++m)
#pragma unroll
      for (int n = 0; n < 4; ++n)
        acc[m][n] = __builtin_amdgcn_mfma_f32_16x16x32_f16(af[m], bfr[n], acc[m][n], 0, 0, 0);
    __syncthreads();
  }

  // epilogue: C/D layout col = l&15, row = (l>>4)*4 + j
  const int orow = (l >> 4) << 2;
  const int ocol = l & 15;
#pragma unroll
  for (int n = 0; n < 4; ++n) {
    const int gn = n0 + (wc << 6) + (n << 4) + ocol;
    const float bs = BIAS ? bias[gn] : 0.f;
#pragma unroll
    for (int m = 0; m < 4; ++m) {
      const int gm = m0 + (wr << 6) + (m << 4) + orow;
#pragma unroll
      for (int j = 0; j < 4; ++j) {
        C[(size_t)(gm + j) * N + gn] = (OutT)(acc[m][n][j] + bs);
      }
    }
  }
}

// ---------------- launch ----------------

extern "C" void kernel_launch(void* const* d_in, const int* in_sizes, int n_in,
                              void* d_out, int out_size, void* d_ws, size_t ws_size,
                              hipStream_t stream) {
  const float* x = (const float*)d_in[0];    // [8,4096,1024]
  const float* Wv = (const float*)d_in[1];   // [1024,1024]
  const float* bv = (const float*)d_in[2];   // [1024]
  const float* Wo = (const float*)d_in[3];   // [1024,1024]
  const float* bo = (const float*)d_in[4];   // [1024]
  const float* nw = (const float*)d_in[5];   // [3]
  float* out = (float*)d_out;

  char* ws = (char*)d_ws;
  f16_t* Wo_h = (f16_t*)(ws);                  // 2 MB
  f16_t* WvT  = (f16_t*)(ws + (2u << 20));     // 2 MB
  f16_t* WcT  = (f16_t*)(ws + (4u << 20));     // 2 MB  (WcT = Wo @ Wv, stored [e][c])
  float* bc   = (float*)(ws + (6u << 20));     // 4 KB
  f16_t* Xavg = (f16_t*)(ws + (8u << 20));     // 64 MB

  // 1) Wo -> fp16
  cvt_f16_kernel<<<dim3(1024), dim3(256), 0, stream>>>(Wo, Wo_h, 1024 * 1024 / 4);
  // 2) Wv -> WvT fp16 (transpose)
  transpose_cvt_kernel<<<dim3(32, 32), dim3(32, 8), 0, stream>>>(Wv, WvT);
  // 3) bconst
  bconst_kernel<<<dim3(1024), dim3(256), 0, stream>>>(Wo, bv, bo, nw, in_sizes[5], bc);
  // 4) xavg (3-tap temporal smoothing, fp16 out)
  xavg_kernel<<<dim3(32768 / 8), dim3(256), 0, stream>>>(x, nw, Xavg);
  // 5) WcT[e][c] = sum_d Wo[e][d] * WvT[c][d]
  gemm_bt_kernel<f16_t, false><<<dim3(64), dim3(256), 0, stream>>>(
      Wo_h, WvT, WcT, (const float*)nullptr, 1024, 1024, 1024);
  // 6) out[r][e] = sum_c Xavg[r][c] * WcT[e][c] + bc[e]
  gemm_bt_kernel<float, true><<<dim3(2048), dim3(256), 0, stream>>>(
      Xavg, WcT, out, bc, 32768, 1024, 1024);
}

// Round 2
// 158.657 us; speedup vs baseline: 1.1854x; 1.1854x over previous
//
#include <hip/hip_runtime.h>
#include <stdint.h>
#include <stddef.h>

typedef _Float16 f16_t;
typedef _Float16 f16x4 __attribute__((ext_vector_type(4)));
typedef _Float16 f16x8 __attribute__((ext_vector_type(8)));
typedef float f32x4 __attribute__((ext_vector_type(4)));

#define AS_G __attribute__((address_space(1)))
#define AS_L __attribute__((address_space(3)))

__device__ __forceinline__ void gload_lds16(const void* g, void* l) {
  __builtin_amdgcn_global_load_lds((AS_G void*)g, (AS_L void*)l, 16, 0, 0);
}

#define FENCE() asm volatile("" ::: "memory")
#define BARX()                            \
  do {                                    \
    FENCE();                              \
    __builtin_amdgcn_s_barrier();         \
    FENCE();                              \
  } while (0)
#define VMCNT(n) asm volatile("s_waitcnt vmcnt(" #n ")" ::: "memory")

// ---------------- small prep kernels ----------------

__global__ void cvt_f16_kernel(const float* __restrict__ in, f16_t* __restrict__ out, int n4) {
  int i = blockIdx.x * blockDim.x + threadIdx.x;
  if (i >= n4) return;
  f32x4 v = ((const f32x4*)in)[i];
  f16x4 o;
  o.x = (f16_t)v.x; o.y = (f16_t)v.y; o.z = (f16_t)v.z; o.w = (f16_t)v.w;
  ((f16x4*)out)[i] = o;
}

__global__ void transpose_cvt_kernel(const float* __restrict__ in, f16_t* __restrict__ out) {
  __shared__ float tile[32][33];
  const int bx = blockIdx.x, by = blockIdx.y;
  const int tx = threadIdx.x, ty = threadIdx.y;
#pragma unroll
  for (int i = 0; i < 32; i += 8)
    tile[ty + i][tx] = in[(size_t)(by * 32 + ty + i) * 1024 + bx * 32 + tx];
  __syncthreads();
#pragma unroll
  for (int i = 0; i < 32; i += 8)
    out[(size_t)(bx * 32 + ty + i) * 1024 + by * 32 + tx] = (f16_t)tile[tx][ty + i];
}

__global__ void bconst_kernel(const float* __restrict__ Wo, const float* __restrict__ bv,
                              const float* __restrict__ bo, const float* __restrict__ nw,
                              int Kw, float* __restrict__ bc) {
  const int e = blockIdx.x;
  const int t = threadIdx.x;
  float sw = 0.f;
  for (int k = 0; k < Kw; ++k) sw += nw[k];
  float p = 0.f;
  for (int d = t; d < 1024; d += 256) p += Wo[(size_t)e * 1024 + d] * bv[d];
  __shared__ float red[256];
  red[t] = p;
  __syncthreads();
  for (int s = 128; s > 0; s >>= 1) {
    if (t < s) red[t] += red[t + s];
    __syncthreads();
  }
  if (t == 0) bc[e] = sw * red[0] + bo[e];
}

__global__ void xavg_kernel(const float* __restrict__ x, const float* __restrict__ nw,
                            f16_t* __restrict__ out) {
  const int T = 4096, D = 1024;
  const int base = blockIdx.x * 8;
  const int t0 = base & (T - 1);
  const int col = threadIdx.x * 4;
  const float w0 = nw[0], w1 = nw[1], w2 = nw[2];
  const float* xb = x + (size_t)base * D + col;
  f32x4 a = *(const f32x4*)(xb + (t0 == 0 ? 0 : -D));
  f32x4 b = *(const f32x4*)(xb);
  f16_t* ob = out + (size_t)base * D + col;
#pragma unroll
  for (int g = 0; g < 8; ++g) {
    f32x4 c;
    if (t0 + g == T - 1) c = b;
    else c = *(const f32x4*)(xb + (size_t)(g + 1) * D);
    f32x4 y = w0 * a + w1 * b + w2 * c;
    f16x4 o;
    o.x = (f16_t)y.x; o.y = (f16_t)y.y; o.z = (f16_t)y.z; o.w = (f16_t)y.w;
    *(f16x4*)(ob + (size_t)g * D) = o;
    a = b;
    b = c;
  }
}

// ---------------- 128^2 GEMM (kept for the small 1024^3 WcT GEMM) ----------------

template <typename OutT, bool BIAS>
__global__ __launch_bounds__(256) void gemm_bt_kernel(const f16_t* __restrict__ A,
                                                      const f16_t* __restrict__ Bt,
                                                      OutT* __restrict__ C,
                                                      const float* __restrict__ bias,
                                                      int M, int N, int K) {
  __shared__ __align__(16) f16_t sA[128 * 32];
  __shared__ __align__(16) f16_t sB[128 * 32];
  const int tid = threadIdx.x;
  const int l = tid & 63;
  const int w = tid >> 6;
  const int wr = w >> 1;
  const int wc = w & 1;
  const int nMT = M >> 7;
  const int bid = blockIdx.x;
  const int mt = bid % nMT;
  const int nt = bid / nMT;
  const int m0 = mt << 7;
  const int n0 = nt << 7;

  const int srow = (w << 4) + (l >> 2);
  const int scol = (l & 3) << 3;
  const size_t aoff0 = (size_t)(m0 + srow) * K + scol;
  const size_t boff0 = (size_t)(n0 + srow) * K + scol;
  f16_t* ldsA = sA + (w << 9);
  f16_t* ldsB = sB + (w << 9);

  f32x4 acc[4][4];
#pragma unroll
  for (int i = 0; i < 4; ++i)
#pragma unroll
    for (int j = 0; j < 4; ++j) acc[i][j] = f32x4{0.f, 0.f, 0.f, 0.f};

  const int ka = (l >> 4) << 3;
  const int ar = (wr << 6) + (l & 15);
  const int br = (wc << 6) + (l & 15);

  const int nK = K >> 5;
  for (int kt = 0; kt < nK; ++kt) {
    const int kb = kt << 5;
    gload_lds16(A + aoff0 + kb, ldsA);
    gload_lds16(A + aoff0 + ((size_t)K << 6) + kb, ldsA + 2048);
    gload_lds16(Bt + boff0 + kb, ldsB);
    gload_lds16(Bt + boff0 + ((size_t)K << 6) + kb, ldsB + 2048);
    __syncthreads();
    f16x8 af[4], bfr[4];
#pragma unroll
    for (int m = 0; m < 4; ++m) af[m] = *(const f16x8*)(sA + ((ar + (m << 4)) << 5) + ka);
#pragma unroll
    for (int n = 0; n < 4; ++n) bfr[n] = *(const f16x8*)(sB + ((br + (n << 4)) << 5) + ka);
#pragma unroll
    for (int m = 0; m < 4; ++m)
#pragma unroll
      for (int n = 0; n < 4; ++n)
        acc[m][n] = __builtin_amdgcn_mfma_f32_16x16x32_f16(af[m], bfr[n], acc[m][n], 0, 0, 0);
    __syncthreads();
  }

  const int orow = (l >> 4) << 2;
  const int ocol = l & 15;
#pragma unroll
  for (int n = 0; n < 4; ++n) {
    const int gn = n0 + (wc << 6) + (n << 4) + ocol;
    const float bs = BIAS ? bias[gn] : 0.f;
#pragma unroll
    for (int m = 0; m < 4; ++m) {
      const int gm = m0 + (wr << 6) + (m << 4) + orow;
#pragma unroll
      for (int j = 0; j < 4; ++j) {
        C[(size_t)(gm + j) * N + gn] = (OutT)(acc[m][n][j] + bs);
      }
    }
  }
}

// ---------------- 256^2 pipelined GEMM: C[M][N] = A[M][K]*Bt[N][K]^T + bias ----------------
// 8 waves (2M x 4N), BK=32, 4-deep LDS ring (128 KB), prefetch distance 3,
// counted vmcnt(8) once per K-tile, raw s_barrier, setprio around MFMA clusters.
// LDS chunk swizzle: chunk ^= (row>>1)&3 applied on gload source AND ds_read (involution).
// Requires: M%256==0, N%256==0, K%32==0, K/32 >= 3.

__device__ __forceinline__ void stage256(const f16_t* __restrict__ g, int K,
                                         f16_t* ldsOp, int w, int l) {
  // one full operand tile 256 rows x 32 f16: 2 x (512 thr x 16 B)
#pragma unroll
  for (int i = 0; i < 2; ++i) {
    const int f = i * 512 + w * 64 + l;
    const int row = f >> 2;
    const int ch = f & 3;
    const int col = ((ch ^ ((row >> 1) & 3)) << 3);  // swizzled source column (f16)
    gload_lds16(g + (size_t)row * K + col, ldsOp + i * 4096 + w * 512);
  }
}

__global__ __launch_bounds__(512, 2) void gemm256_kernel(const f16_t* __restrict__ A,
                                                         const f16_t* __restrict__ Bt,
                                                         float* __restrict__ C,
                                                         const float* __restrict__ bias,
                                                         int M, int N, int K) {
  __shared__ __align__(16) f16_t lds[4 * 16384];  // 4 bufs x (A 8192 + B 8192) f16 = 128 KB
  const int tid = threadIdx.x;
  const int l = tid & 63;
  const int w = tid >> 6;       // 0..7
  const int wr = w >> 2;        // 0..1 -> 128-row half
  const int wc = w & 3;         // 0..3 -> 64-col slice

  // XCD-aware swizzle (gridDim.x % 8 == 0 here: 512)
  const int nwg = gridDim.x;
  const int cpx = nwg >> 3;
  const int swz = (blockIdx.x & 7) * cpx + (blockIdx.x >> 3);
  const int nNT = N >> 8;
  const int mt = swz / nNT;
  const int nt = swz % nNT;
  const int m0 = mt << 8;
  const int n0 = nt << 8;

  const f16_t* Apanel = A + (size_t)m0 * K;
  const f16_t* Bpanel = Bt + (size_t)n0 * K;

  const int lr = l & 15;
  const int q = l >> 4;
  const int sw = ((q ^ ((lr >> 1) & 3)) << 3);  // lane-constant swizzled k-offset (f16)

  f32x4 acc[8][4];
#pragma unroll
  for (int m = 0; m < 8; ++m)
#pragma unroll
    for (int n = 0; n < 4; ++n) acc[m][n] = f32x4{0.f, 0.f, 0.f, 0.f};

  const int nK = K >> 5;

  // prologue: stage tiles 0,1,2 into ring bufs 0,1,2 (12 vmem instrs/wave)
  for (int t = 0; t < 3; ++t) {
    f16_t* buf = lds + (t & 3) * 16384;
    stage256(Apanel + (t << 5), K, buf, w, l);
    stage256(Bpanel + (t << 5), K, buf + 8192, w, l);
  }
  VMCNT(8);  // tile 0 landed (tiles 1,2 = 8 instrs may remain in flight)
  BARX();

  for (int t = 0; t < nK; ++t) {
    f16_t* sA = lds + (t & 3) * 16384;
    f16_t* sB = sA + 8192;

    // ---- phase A: read A m0-3 + all B, stage A of tile t+3 ----
    f16x8 bf[4], af[4];
#pragma unroll
    for (int n = 0; n < 4; ++n)
      bf[n] = *(const f16x8*)(sB + (((wc << 6) + (n << 4) + lr) << 5) + sw);
#pragma unroll
    for (int m = 0; m < 4; ++m)
      af[m] = *(const f16x8*)(sA + (((wr << 7) + (m << 4) + lr) << 5) + sw);
    if (t + 3 < nK) {
      f16_t* nbuf = lds + ((t + 3) & 3) * 16384;
      stage256(Apanel + ((size_t)(t + 3) << 5), K, nbuf, w, l);
    }
    BARX();
    __builtin_amdgcn_s_setprio(1);
#pragma unroll
    for (int m = 0; m < 4; ++m)
#pragma unroll
      for (int n = 0; n < 4; ++n)
        acc[m][n] = __builtin_amdgcn_mfma_f32_16x16x32_f16(af[m], bf[n], acc[m][n], 0, 0, 0);
    __builtin_amdgcn_s_setprio(0);
    BARX();

    // ---- phase B: read A m4-7, stage B of tile t+3 ----
    f16x8 ag[4];
#pragma unroll
    for (int m = 0; m < 4; ++m)
      ag[m] = *(const f16x8*)(sA + (((wr << 7) + 64 + (m << 4) + lr) << 5) + sw);
    if (t + 3 < nK) {
      f16_t* nbuf = lds + ((t + 3) & 3) * 16384;
      stage256(Bpanel + ((size_t)(t + 3) << 5), K, nbuf + 8192, w, l);
    }
    BARX();
    __builtin_amdgcn_s_setprio(1);
#pragma unroll
    for (int m = 0; m < 4; ++m)
#pragma unroll
      for (int n = 0; n < 4; ++n)
        acc[m + 4][n] = __builtin_amdgcn_mfma_f32_16x16x32_f16(ag[m], bf[n], acc[m + 4][n], 0, 0, 0);
    __builtin_amdgcn_s_setprio(0);
    VMCNT(8);  // tile t+1 fully landed; tiles t+2,t+3 (<=8 instrs) may fly
    BARX();
  }

  // epilogue
  float bs[4];
#pragma unroll
  for (int n = 0; n < 4; ++n) bs[n] = bias[n0 + (wc << 6) + (n << 4) + lr];
#pragma unroll
  for (int m = 0; m < 8; ++m) {
    const int gm = m0 + (wr << 7) + (m << 4) + (q << 2);
#pragma unroll
    for (int j = 0; j < 4; ++j) {
      float* Crow = C + (size_t)(gm + j) * N + n0 + (wc << 6) + lr;
#pragma unroll
      for (int n = 0; n < 4; ++n) Crow[n << 4] = acc[m][n][j] + bs[n];
    }
  }
}

// ---------------- launch ----------------

extern "C" void kernel_launch(void* const* d_in, const int* in_sizes, int n_in,
                              void* d_out, int out_size, void* d_ws, size_t ws_size,
                              hipStream_t stream) {
  const float* x = (const float*)d_in[0];    // [8,4096,1024]
  const float* Wv = (const float*)d_in[1];   // [1024,1024]
  const float* bv = (const float*)d_in[2];   // [1024]
  const float* Wo = (const float*)d_in[3];   // [1024,1024]
  const float* bo = (const float*)d_in[4];   // [1024]
  const float* nw = (const float*)d_in[5];   // [3]
  float* out = (float*)d_out;

  char* ws = (char*)d_ws;
  f16_t* Wo_h = (f16_t*)(ws);                  // 2 MB
  f16_t* WvT  = (f16_t*)(ws + (2u << 20));     // 2 MB
  f16_t* WcT  = (f16_t*)(ws + (4u << 20));     // 2 MB  (WcT = Wo @ Wv, stored [e][c])
  float* bc   = (float*)(ws + (6u << 20));     // 4 KB
  f16_t* Xavg = (f16_t*)(ws + (8u << 20));     // 64 MB

  cvt_f16_kernel<<<dim3(1024), dim3(256), 0, stream>>>(Wo, Wo_h, 1024 * 1024 / 4);
  transpose_cvt_kernel<<<dim3(32, 32), dim3(32, 8), 0, stream>>>(Wv, WvT);
  bconst_kernel<<<dim3(1024), dim3(256), 0, stream>>>(Wo, bv, bo, nw, in_sizes[5], bc);
  xavg_kernel<<<dim3(32768 / 8), dim3(256), 0, stream>>>(x, nw, Xavg);
  // WcT[e][c] = sum_d Wo[e][d] * WvT[c][d]  (small 1024^3 -> 128^2 kernel, 64 blocks)
  gemm_bt_kernel<f16_t, false><<<dim3(64), dim3(256), 0, stream>>>(
      Wo_h, WvT, WcT, (const float*)nullptr, 1024, 1024, 1024);
  // out[r][e] = sum_c Xavg[r][c] * WcT[e][c] + bc[e]  (pipelined 256^2 kernel, 512 blocks)
  gemm256_kernel<<<dim3(512), dim3(512), 0, stream>>>(
      Xavg, WcT, out, bc, 32768, 1024, 1024);
}

// Round 3
// 155.166 us; speedup vs baseline: 1.2120x; 1.0225x over previous
//
#include <hip/hip_runtime.h>
#include <stdint.h>
#include <stddef.h>

typedef _Float16 f16_t;
typedef _Float16 f16x4 __attribute__((ext_vector_type(4)));
typedef _Float16 f16x8 __attribute__((ext_vector_type(8)));
typedef float f32x4 __attribute__((ext_vector_type(4)));

#define AS_G __attribute__((address_space(1)))
#define AS_L __attribute__((address_space(3)))

__device__ __forceinline__ void gload_lds16(const void* g, void* l) {
  __builtin_amdgcn_global_load_lds((AS_G void*)g, (AS_L void*)l, 16, 0, 0);
}

#define FENCE() asm volatile("" ::: "memory")
#define BARX()                            \
  do {                                    \
    FENCE();                              \
    __builtin_amdgcn_s_barrier();         \
    FENCE();                              \
  } while (0)
#define VMCNT(n) asm volatile("s_waitcnt vmcnt(" #n ")" ::: "memory")
#define LGKM0() asm volatile("s_waitcnt lgkmcnt(0)" ::: "memory")

// ---------------- small prep kernels ----------------

__global__ void cvt_f16_kernel(const float* __restrict__ in, f16_t* __restrict__ out, int n4) {
  int i = blockIdx.x * blockDim.x + threadIdx.x;
  if (i >= n4) return;
  f32x4 v = ((const f32x4*)in)[i];
  f16x4 o;
  o.x = (f16_t)v.x; o.y = (f16_t)v.y; o.z = (f16_t)v.z; o.w = (f16_t)v.w;
  ((f16x4*)out)[i] = o;
}

__global__ void transpose_cvt_kernel(const float* __restrict__ in, f16_t* __restrict__ out) {
  __shared__ float tile[32][33];
  const int bx = blockIdx.x, by = blockIdx.y;
  const int tx = threadIdx.x, ty = threadIdx.y;
#pragma unroll
  for (int i = 0; i < 32; i += 8)
    tile[ty + i][tx] = in[(size_t)(by * 32 + ty + i) * 1024 + bx * 32 + tx];
  __syncthreads();
#pragma unroll
  for (int i = 0; i < 32; i += 8)
    out[(size_t)(bx * 32 + ty + i) * 1024 + by * 32 + tx] = (f16_t)tile[tx][ty + i];
}

__global__ void bconst_kernel(const float* __restrict__ Wo, const float* __restrict__ bv,
                              const float* __restrict__ bo, const float* __restrict__ nw,
                              int Kw, float* __restrict__ bc) {
  const int e = blockIdx.x;
  const int t = threadIdx.x;
  float sw = 0.f;
  for (int k = 0; k < Kw; ++k) sw += nw[k];
  float p = 0.f;
  for (int d = t; d < 1024; d += 256) p += Wo[(size_t)e * 1024 + d] * bv[d];
  __shared__ float red[256];
  red[t] = p;
  __syncthreads();
  for (int s = 128; s > 0; s >>= 1) {
    if (t < s) red[t] += red[t + s];
    __syncthreads();
  }
  if (t == 0) bc[e] = sw * red[0] + bo[e];
}

// ---------------- 128^2 GEMM (small 1024^3 WcT GEMM) ----------------

template <typename OutT, bool BIAS>
__global__ __launch_bounds__(256) void gemm_bt_kernel(const f16_t* __restrict__ A,
                                                      const f16_t* __restrict__ Bt,
                                                      OutT* __restrict__ C,
                                                      const float* __restrict__ bias,
                                                      int M, int N, int K) {
  __shared__ __align__(16) f16_t sA[128 * 32];
  __shared__ __align__(16) f16_t sB[128 * 32];
  const int tid = threadIdx.x;
  const int l = tid & 63;
  const int w = tid >> 6;
  const int wr = w >> 1;
  const int wc = w & 1;
  const int nMT = M >> 7;
  const int bid = blockIdx.x;
  const int mt = bid % nMT;
  const int nt = bid / nMT;
  const int m0 = mt << 7;
  const int n0 = nt << 7;

  const int srow = (w << 4) + (l >> 2);
  const int scol = (l & 3) << 3;
  const size_t aoff0 = (size_t)(m0 + srow) * K + scol;
  const size_t boff0 = (size_t)(n0 + srow) * K + scol;
  f16_t* ldsA = sA + (w << 9);
  f16_t* ldsB = sB + (w << 9);

  f32x4 acc[4][4];
#pragma unroll
  for (int i = 0; i < 4; ++i)
#pragma unroll
    for (int j = 0; j < 4; ++j) acc[i][j] = f32x4{0.f, 0.f, 0.f, 0.f};

  const int ka = (l >> 4) << 3;
  const int ar = (wr << 6) + (l & 15);
  const int br = (wc << 6) + (l & 15);

  const int nK = K >> 5;
  for (int kt = 0; kt < nK; ++kt) {
    const int kb = kt << 5;
    gload_lds16(A + aoff0 + kb, ldsA);
    gload_lds16(A + aoff0 + ((size_t)K << 6) + kb, ldsA + 2048);
    gload_lds16(Bt + boff0 + kb, ldsB);
    gload_lds16(Bt + boff0 + ((size_t)K << 6) + kb, ldsB + 2048);
    __syncthreads();
    f16x8 af[4], bfr[4];
#pragma unroll
    for (int m = 0; m < 4; ++m) af[m] = *(const f16x8*)(sA + ((ar + (m << 4)) << 5) + ka);
#pragma unroll
    for (int n = 0; n < 4; ++n) bfr[n] = *(const f16x8*)(sB + ((br + (n << 4)) << 5) + ka);
#pragma unroll
    for (int m = 0; m < 4; ++m)
#pragma unroll
      for (int n = 0; n < 4; ++n)
        acc[m][n] = __builtin_amdgcn_mfma_f32_16x16x32_f16(af[m], bfr[n], acc[m][n], 0, 0, 0);
    __syncthreads();
  }

  const int orow = (l >> 4) << 2;
  const int ocol = l & 15;
#pragma unroll
  for (int n = 0; n < 4; ++n) {
    const int gn = n0 + (wc << 6) + (n << 4) + ocol;
    const float bs = BIAS ? bias[gn] : 0.f;
#pragma unroll
    for (int m = 0; m < 4; ++m) {
      const int gm = m0 + (wr << 6) + (m << 4) + orow;
#pragma unroll
      for (int j = 0; j < 4; ++j) {
        C[(size_t)(gm + j) * N + gn] = (OutT)(acc[m][n][j] + bs);
      }
    }
  }
}

// ---------------- fused 3-tap + 256^2 pipelined GEMM ----------------
// out[r][e] = sum_c (w0*x[r-1]+w1*x[r]+w2*x[r+1])[c] * WcT[e][c] + bc[e]
// A staged in-register (f32 loads + 3-tap + cvt f16) -> padded LDS (stride 40 f16),
// issue-early/write-late (T14), distance-1-tile regs. B via gload_lds ring-3,
// XOR source swizzle (proven conflict-free). Counted vmcnt only; no vmcnt(0) in loop.

__device__ __forceinline__ void stageB(const f16_t* __restrict__ g, int K,
                                       f16_t* ldsOp, int w, int l) {
#pragma unroll
  for (int i = 0; i < 2; ++i) {
    const int f = i * 512 + w * 64 + l;
    const int row = f >> 2;
    const int ch = f & 3;
    const int col = ((ch ^ ((row >> 1) & 3)) << 3);
    gload_lds16(g + (size_t)row * K + col, ldsOp + i * 4096 + w * 512);
  }
}

__global__ __launch_bounds__(512, 2) void gemm_fused_kernel(
    const float* __restrict__ X, const f16_t* __restrict__ Bt,
    float* __restrict__ C, const float* __restrict__ bias,
    const float* __restrict__ nw) {
  constexpr int N = 1024, K = 1024, T = 4096;
  constexpr int nK = K >> 5;   // 32
  constexpr int AST = 40;      // padded A row stride (f16)
  __shared__ __align__(16) f16_t sA[2 * 256 * AST];  // 40 KB
  __shared__ __align__(16) f16_t sB[3 * 8192];       // 48 KB

  const int tid = threadIdx.x;
  const int l = tid & 63;
  const int w = tid >> 6;
  const int wr = w >> 2;
  const int wc = w & 3;
  const int lr = l & 15;
  const int q = l >> 4;

  const int cpx = (int)gridDim.x >> 3;
  const int swz = ((int)blockIdx.x & 7) * cpx + ((int)blockIdx.x >> 3);
  const int nNT = N >> 8;
  const int mt = swz / nNT;
  const int nt = swz % nNT;
  const int m0 = mt << 8;
  const int n0 = nt << 8;

  const f16_t* Bpanel = Bt + (size_t)n0 * K;

  // --- fused A staging mapping: thread -> row-pair rp, col-chunk cch ---
  const int rp = tid >> 2;        // 0..127 -> rows 2rp, 2rp+1
  const int cch = tid & 3;        // 8-f32 chunk
  const bool bst = (m0 & (T - 1)) == 0;
  const bool ben = ((m0 + 256) & (T - 1)) == 0;
  const int r0 = rp << 1, r1 = r0 + 1;
  const int rm = (rp == 0 && bst) ? 0 : r0 - 1;
  const int r2 = (rp == 127 && ben) ? r1 : r1 + 1;
  const float* pxm = X + (size_t)(m0 + rm) * K + (cch << 3);
  const float* px0 = X + (size_t)(m0 + r0) * K + (cch << 3);
  const float* px1 = X + (size_t)(m0 + r1) * K + (cch << 3);
  const float* px2 = X + (size_t)(m0 + r2) * K + (cch << 3);
  const float w0 = nw[0], w1 = nw[1], w2 = nw[2];

  f32x4 va0, va1, vb0, vb1, vc0, vc1, vd0, vd1;

#define ALOAD(kt)                                          \
  do {                                                     \
    const int off_ = (kt) << 5;                            \
    va0 = *(const f32x4*)(pxm + off_);                     \
    va1 = *(const f32x4*)(pxm + off_ + 4);                 \
    vb0 = *(const f32x4*)(px0 + off_);                     \
    vb1 = *(const f32x4*)(px0 + off_ + 4);                 \
    vc0 = *(const f32x4*)(px1 + off_);                     \
    vc1 = *(const f32x4*)(px1 + off_ + 4);                 \
    vd0 = *(const f32x4*)(px2 + off_);                     \
    vd1 = *(const f32x4*)(px2 + off_ + 4);                 \
  } while (0)

#define AWRITE(buf)                                                      \
  do {                                                                   \
    f16_t* dst_ = sA + (buf) * (256 * AST);                              \
    f32x4 t00 = w0 * va0 + w1 * vb0 + w2 * vc0;                          \
    f32x4 t01 = w0 * va1 + w1 * vb1 + w2 * vc1;                          \
    f32x4 t10 = w0 * vb0 + w1 * vc0 + w2 * vd0;                          \
    f32x4 t11 = w0 * vb1 + w1 * vc1 + w2 * vd1;                          \
    f16x8 y0_, y1_;                                                      \
    _Pragma("unroll") for (int e = 0; e < 4; ++e) {                      \
      y0_[e] = (f16_t)t00[e]; y0_[e + 4] = (f16_t)t01[e];                \
      y1_[e] = (f16_t)t10[e]; y1_[e + 4] = (f16_t)t11[e];                \
    }                                                                    \
    *(f16x8*)(dst_ + r0 * AST + (cch << 3)) = y0_;                       \
    *(f16x8*)(dst_ + r1 * AST + (cch << 3)) = y1_;                       \
  } while (0)

  f32x4 acc[8][4];
#pragma unroll
  for (int m = 0; m < 8; ++m)
#pragma unroll
    for (int n = 0; n < 4; ++n) acc[m][n] = f32x4{0.f, 0.f, 0.f, 0.f};

  const int swB = (q ^ ((lr >> 1) & 3)) << 3;  // B read swizzle (matches stageB source)

  // ---- prologue ----
  ALOAD(0);                          // 8 vmem
  stageB(Bpanel, K, sB, w, l);       // 2  (tile 0 -> buf 0)
  stageB(Bpanel + 32, K, sB + 8192, w, l);  // 2  (tile 1 -> buf 1)
  VMCNT(4);                          // ALOAD(0) landed (B0,B1 may fly)
  AWRITE(0);
  ALOAD(1);                          // 8
  VMCNT(10);                         // B0 landed (B1 + ALOAD(1) = 10 fly)
  LGKM0();
  BARX();

  for (int t = 0; t < nK; ++t) {
    f16_t* cA = sA + (t & 1) * (256 * AST);
    f16_t* cB = sB + (t % 3) * 8192;

    // ---- phase A ----
    f16x8 bf[4], af[4];
#pragma unroll
    for (int n = 0; n < 4; ++n)
      bf[n] = *(const f16x8*)(cB + (((wc << 6) + (n << 4) + lr) << 5) + swB);
#pragma unroll
    for (int m = 0; m < 4; ++m)
      af[m] = *(const f16x8*)(cA + ((wr << 7) + (m << 4) + lr) * AST + (q << 3));
    if (t + 2 < nK) stageB(Bpanel + ((t + 2) << 5), K, sB + ((t + 2) % 3) * 8192, w, l);
    BARX();
    __builtin_amdgcn_s_setprio(1);
#pragma unroll
    for (int m = 0; m < 4; ++m)
#pragma unroll
      for (int n = 0; n < 4; ++n)
        acc[m][n] = __builtin_amdgcn_mfma_f32_16x16x32_f16(af[m], bf[n], acc[m][n], 0, 0, 0);
    __builtin_amdgcn_s_setprio(0);
    BARX();

    // ---- phase B ----
    f16x8 ag[4];
#pragma unroll
    for (int m = 0; m < 4; ++m)
      ag[m] = *(const f16x8*)(cA + ((wr << 7) + 64 + (m << 4) + lr) * AST + (q << 3));
    VMCNT(2);                        // ALOAD(t+1) landed (only B(t+2) flies)
    if (t + 1 < nK) AWRITE((t + 1) & 1);
    if (t + 2 < nK) ALOAD(t + 2);    // 8 vmem, regs free after AWRITE
    BARX();
    __builtin_amdgcn_s_setprio(1);
#pragma unroll
    for (int m = 0; m < 4; ++m)
#pragma unroll
      for (int n = 0; n < 4; ++n)
        acc[m + 4][n] = __builtin_amdgcn_mfma_f32_16x16x32_f16(ag[m], bf[n], acc[m + 4][n], 0, 0, 0);
    __builtin_amdgcn_s_setprio(0);
    LGKM0();                         // AWRITE visible before next-iter reads
    BARX();
  }

  // ---- epilogue ----
  float bs[4];
#pragma unroll
  for (int n = 0; n < 4; ++n) bs[n] = bias[n0 + (wc << 6) + (n << 4) + lr];
#pragma unroll
  for (int m = 0; m < 8; ++m) {
    const int gm = m0 + (wr << 7) + (m << 4) + (q << 2);
#pragma unroll
    for (int j = 0; j < 4; ++j) {
      float* Crow = C + (size_t)(gm + j) * N + n0 + (wc << 6) + lr;
#pragma unroll
      for (int n = 0; n < 4; ++n) Crow[n << 4] = acc[m][n][j] + bs[n];
    }
  }
#undef ALOAD
#undef AWRITE
}

// ---------------- launch ----------------

extern "C" void kernel_launch(void* const* d_in, const int* in_sizes, int n_in,
                              void* d_out, int out_size, void* d_ws, size_t ws_size,
                              hipStream_t stream) {
  const float* x = (const float*)d_in[0];    // [8,4096,1024]
  const float* Wv = (const float*)d_in[1];   // [1024,1024]
  const float* bv = (const float*)d_in[2];   // [1024]
  const float* Wo = (const float*)d_in[3];   // [1024,1024]
  const float* bo = (const float*)d_in[4];   // [1024]
  const float* nw = (const float*)d_in[5];   // [3]
  float* out = (float*)d_out;

  char* ws = (char*)d_ws;
  f16_t* Wo_h = (f16_t*)(ws);                  // 2 MB
  f16_t* WvT  = (f16_t*)(ws + (2u << 20));     // 2 MB
  f16_t* WcT  = (f16_t*)(ws + (4u << 20));     // 2 MB (WcT = Wo @ Wv, [e][c])
  float* bc   = (float*)(ws + (6u << 20));     // 4 KB

  cvt_f16_kernel<<<dim3(1024), dim3(256), 0, stream>>>(Wo, Wo_h, 1024 * 1024 / 4);
  transpose_cvt_kernel<<<dim3(32, 32), dim3(32, 8), 0, stream>>>(Wv, WvT);
  bconst_kernel<<<dim3(1024), dim3(256), 0, stream>>>(Wo, bv, bo, nw, in_sizes[5], bc);
  // WcT[e][c] = sum_d Wo[e][d] * WvT[c][d]
  gemm_bt_kernel<f16_t, false><<<dim3(64), dim3(256), 0, stream>>>(
      Wo_h, WvT, WcT, (const float*)nullptr, 1024, 1024, 1024);
  // fused: out = (3-tap x) @ WcT^T + bc
  gemm_fused_kernel<<<dim3(512), dim3(512), 0, stream>>>(x, WcT, out, bc, nw);
}